// Round 1
// baseline (448.998 us; speedup 1.0000x reference)
//
#include <hip/hip_runtime.h>

typedef _Float16 f16;
typedef __attribute__((ext_vector_type(8))) _Float16 f16x8;
typedef __attribute__((ext_vector_type(4))) _Float16 f16x4;
typedef __attribute__((ext_vector_type(4))) float    f32x4;

#define B_ROWS 16384
#define MPAD   17408   // 16384 + 8 clusters * 128-row tile padding
#define MTILES 136

typedef __attribute__((address_space(1))) void as1_void;
typedef __attribute__((address_space(3))) void as3_void;

__device__ __forceinline__ void gl_lds16(const void* g, void* l) {
    __builtin_amdgcn_global_load_lds((const as1_void*)g, (as3_void*)l, 16, 0, 0);
}

// ---------------- setup kernels ----------------

__global__ __launch_bounds__(256) void k_init(int* rowmap, int* counts, int* cursors, f16* zerobuf) {
    int i = blockIdx.x * 256 + threadIdx.x;
    if (i < MPAD) rowmap[i] = -1;
    if (i < 8) { counts[i] = 0; cursors[i] = 0; }
    if (i < 16) zerobuf[i] = (f16)0.f;
}

__global__ __launch_bounds__(256) void k_hist(const int* __restrict__ lbl, int* counts) {
    __shared__ int h[8];
    if (threadIdx.x < 8) h[threadIdx.x] = 0;
    __syncthreads();
    int i = blockIdx.x * 256 + threadIdx.x;
    if (i < B_ROWS) atomicAdd(&h[lbl[i]], 1);
    __syncthreads();
    if (threadIdx.x < 8) atomicAdd(&counts[threadIdx.x], h[threadIdx.x]);
}

__global__ void k_offsets(const int* __restrict__ counts, int* offs, int* tilec) {
    __shared__ int so[9];
    if (threadIdx.x == 0) {
        int o = 0;
        for (int c = 0; c < 8; ++c) { so[c] = o; o += (counts[c] + 127) & ~127; }
        so[8] = o;
        for (int c = 0; c < 9; ++c) offs[c] = so[c];
    }
    __syncthreads();
    int t = threadIdx.x;
    if (t < MTILES) {
        int row = t * 128, c = 7;
        for (int cc = 0; cc < 8; ++cc)
            if (row >= so[cc] && row < so[cc + 1]) c = cc;
        tilec[t] = c;
    }
}

__global__ __launch_bounds__(256) void k_scatter(const int* __restrict__ lbl, const int* __restrict__ offs,
                                                 int* cursors, int* rowmap) {
    int i = blockIdx.x * 256 + threadIdx.x;
    if (i < B_ROWS) {
        int c = lbl[i];
        int pos = atomicAdd(&cursors[c], 1);
        rowmap[offs[c] + pos] = i;
    }
}

__global__ __launch_bounds__(256) void k_cvt(const float* __restrict__ s, f16* __restrict__ d, int n4) {
    int i = blockIdx.x * 256 + threadIdx.x;
    if (i < n4) {
        float4 v = ((const float4*)s)[i];
        f16x4 o = {(f16)v.x, (f16)v.y, (f16)v.z, (f16)v.w};
        ((f16x4*)d)[i] = o;
    }
}

// transpose+convert: src [K,N] fp32 -> dst [N,K] f16 (per cluster in grid.z)
__global__ __launch_bounds__(256) void tq_k(const float* __restrict__ src, f16* __restrict__ dst,
                                            int K, int N, long srcCS, long dstCS) {
    __shared__ float t[32][33];
    src += (size_t)blockIdx.z * srcCS;
    dst += (size_t)blockIdx.z * dstCS;
    int n0 = blockIdx.x * 32, k0 = blockIdx.y * 32;
    int tx = threadIdx.x & 31, ty = threadIdx.x >> 5;
    #pragma unroll
    for (int i = 0; i < 32; i += 8)
        t[ty + i][tx] = src[(size_t)(k0 + ty + i) * N + n0 + tx];
    __syncthreads();
    #pragma unroll
    for (int i = 0; i < 32; i += 8)
        dst[(size_t)(n0 + ty + i) * K + k0 + tx] = (f16)t[tx][ty + i];
}

__global__ void k_biasz(const float* __restrict__ mb_, const float* __restrict__ lb_, float* bz) {
    int i = threadIdx.x;
    if (i < 64) bz[i] = mb_[i];
    else if (i < 128) bz[i] = lb_[i - 64];
}

__global__ __launch_bounds__(256) void k_reparam(const f16* __restrict__ muv, const float* __restrict__ eps,
                                                 const int* __restrict__ rowmap, f16* __restrict__ z) {
    int i = blockIdx.x * 256 + threadIdx.x;   // MPAD*64 exactly
    int p = i >> 6, j = i & 63;
    int g = rowmap[p];
    float e  = (g >= 0) ? eps[(size_t)g * 64 + j] : 0.f;
    float mu = (float)muv[(size_t)p * 128 + j];
    float lv = (float)muv[(size_t)p * 128 + 64 + j];
    z[i] = (f16)(mu + expf(0.5f * lv) * e);
}

// ---------------- MFMA GEMM (m97 structure: 128x128 tile, BK=32, global_load_lds) ----------------
// A [*, K] f16 (GATHER: rows via rowmap), Wt [C?, N, K] f16, bias [C?, N] fp32.
// Out f16 [MPAD, N]  (SCATTER: fp32 d_out rows via rowmap)

template<int GATHER, int PERW, int RELU, int SCATTER>
__global__ __launch_bounds__(256) void gemm_k(
    const f16* __restrict__ A, const f16* __restrict__ Wt,
    const float* __restrict__ bias, f16* __restrict__ Out, float* __restrict__ OutF,
    const int* __restrict__ rowmap, const int* __restrict__ tilec,
    const f16* __restrict__ zerobuf, int K, int N)
{
    __shared__ __align__(16) f16 lA[128 * 32];
    __shared__ __align__(16) f16 lB[128 * 32];
    const int tid  = threadIdx.x;
    const int wave = tid >> 6;
    const int lane = tid & 63;
    const int tm = blockIdx.x, tn = blockIdx.y;
    const int r0 = tm * 128, n0 = tn * 128;

    const f16* wb = Wt;
    const float* bb = bias;
    if (PERW) {
        int c = tilec[tm];
        wb += (size_t)c * K * N;
        bb += (size_t)c * N;
    }

    // staging: 256 threads * 16B = one 64-row half-tile per pass; 2 passes each for A and B
    const int srow = tid >> 2;            // 0..63
    const int skk  = (tid & 3) * 8;       // 0,8,16,24 halves
    const f16 *pa0, *pa1;
    int stepA0 = 32, stepA1 = 32;
    if (GATHER) {
        int g0 = rowmap[r0 + srow];
        int g1 = rowmap[r0 + 64 + srow];
        pa0 = (g0 >= 0) ? (A + (size_t)g0 * K + skk) : zerobuf;
        pa1 = (g1 >= 0) ? (A + (size_t)g1 * K + skk) : zerobuf;
        if (g0 < 0) stepA0 = 0;
        if (g1 < 0) stepA1 = 0;
    } else {
        pa0 = A + (size_t)(r0 + srow) * K + skk;
        pa1 = A + (size_t)(r0 + 64 + srow) * K + skk;
    }
    const f16* pb0 = wb + (size_t)(n0 + srow) * K + skk;
    const f16* pb1 = wb + (size_t)(n0 + 64 + srow) * K + skk;

    // wave-uniform LDS staging bases (global_load_lds writes base + lane*16)
    char* lAw = (char*)lA + wave * 1024;
    char* lBw = (char*)lB + wave * 1024;

    const int mb = (wave >> 1) * 64;
    const int nb = (wave & 1) * 64;
    const int quad = lane >> 4;
    const int r16  = lane & 15;

    f32x4 acc[4][4];
    #pragma unroll
    for (int i = 0; i < 4; ++i)
        #pragma unroll
        for (int j = 0; j < 4; ++j)
            acc[i][j] = (f32x4){0.f, 0.f, 0.f, 0.f};

    const int nk = K >> 5;
    for (int kb = 0; kb < nk; ++kb) {
        gl_lds16(pa0, lAw);
        gl_lds16(pa1, lAw + 4096);
        gl_lds16(pb0, lBw);
        gl_lds16(pb1, lBw + 4096);
        __syncthreads();   // compiler emits vmcnt(0) drain before s_barrier
        f16x8 af[4], bf[4];
        #pragma unroll
        for (int i = 0; i < 4; ++i)
            af[i] = *(const f16x8*)(lA + (mb + i * 16 + r16) * 32 + quad * 8);
        #pragma unroll
        for (int j = 0; j < 4; ++j)
            bf[j] = *(const f16x8*)(lB + (nb + j * 16 + r16) * 32 + quad * 8);
        #pragma unroll
        for (int i = 0; i < 4; ++i)
            #pragma unroll
            for (int j = 0; j < 4; ++j)
                acc[i][j] = __builtin_amdgcn_mfma_f32_16x16x32_f16(af[i], bf[j], acc[i][j], 0, 0, 0);
        __syncthreads();
        pa0 += stepA0; pa1 += stepA1; pb0 += 32; pb1 += 32;
    }

    float bv[4];
    #pragma unroll
    for (int j = 0; j < 4; ++j) bv[j] = bb[n0 + nb + j * 16 + r16];

    #pragma unroll
    for (int i = 0; i < 4; ++i) {
        #pragma unroll
        for (int r = 0; r < 4; ++r) {
            int orow = r0 + mb + i * 16 + quad * 4 + r;
            int g = 0;
            if (SCATTER) g = rowmap[orow];
            #pragma unroll
            for (int j = 0; j < 4; ++j) {
                int ocol = n0 + nb + j * 16 + r16;
                float v = acc[i][j][r] + bv[j];
                if (RELU) v = fmaxf(v, 0.f);
                if (SCATTER) {
                    if (g >= 0) OutF[(size_t)g * N + ocol] = v;
                } else {
                    Out[(size_t)orow * N + ocol] = (f16)v;
                }
            }
        }
    }
}

// ---------------- launch ----------------

extern "C" void kernel_launch(void* const* d_in, const int* in_sizes, int n_in,
                              void* d_out, int out_size, void* d_ws, size_t ws_size,
                              hipStream_t stream) {
    const float* x      = (const float*)d_in[0];
    const int*   lbl    = (const int*)  d_in[1];
    const float* eps    = (const float*)d_in[2];
    const float* enc_W0 = (const float*)d_in[3];
    const float* enc_b0 = (const float*)d_in[4];
    const float* enc_Wu = (const float*)d_in[5];
    const float* enc_bu = (const float*)d_in[6];
    const float* enc_W2 = (const float*)d_in[7];
    const float* enc_b2 = (const float*)d_in[8];
    const float* mu_W   = (const float*)d_in[9];
    const float* mu_b   = (const float*)d_in[10];
    const float* lv_W   = (const float*)d_in[11];
    const float* lv_b   = (const float*)d_in[12];
    const float* dWu0   = (const float*)d_in[13];
    const float* dbu0   = (const float*)d_in[14];
    const float* dW1    = (const float*)d_in[15];
    const float* db1    = (const float*)d_in[16];
    const float* dWu2   = (const float*)d_in[17];
    const float* dbu2   = (const float*)d_in[18];
    const float* finW   = (const float*)d_in[19];
    const float* finb   = (const float*)d_in[20];
    float* out = (float*)d_out;
    (void)in_sizes; (void)n_in; (void)out_size; (void)ws_size;

    char* base = (char*)d_ws;
    size_t off = 0;
    auto alloc = [&](size_t bytes) { char* r = base + off; off = (off + bytes + 255) & ~(size_t)255; return r; };
    f16* xh     = (f16*)alloc((size_t)B_ROWS * 512 * 2);
    f16* buf1   = (f16*)alloc((size_t)MPAD * 1024 * 2);  // h1 / h6
    f16* buf2   = (f16*)alloc((size_t)MPAD * 512 * 2);   // h2 / h5
    f16* buf3   = (f16*)alloc((size_t)MPAD * 256 * 2);   // h3 / h4
    f16* muv    = (f16*)alloc((size_t)MPAD * 128 * 2);   // [mu|logvar]
    f16* zb     = (f16*)alloc((size_t)MPAD * 64 * 2);
    f16* w0t    = (f16*)alloc(1024ul * 512 * 2);
    f16* wut    = (f16*)alloc(8ul * 512 * 1024 * 2);
    f16* w2t    = (f16*)alloc(256ul * 512 * 2);
    f16* wzt    = (f16*)alloc(128ul * 256 * 2);
    f16* wd0t   = (f16*)alloc(8ul * 256 * 64 * 2);
    f16* wd1t   = (f16*)alloc(512ul * 256 * 2);
    f16* wd2t   = (f16*)alloc(8ul * 1024 * 512 * 2);
    f16* wft    = (f16*)alloc(8ul * 512 * 1024 * 2);
    float* bz   = (float*)alloc(128 * 4);
    int* rowmap = (int*)alloc(MPAD * 4);
    int* counts = (int*)alloc(32);
    int* offs   = (int*)alloc(64);
    int* cursors= (int*)alloc(32);
    int* tilec  = (int*)alloc(MTILES * 4);
    f16* zerob  = (f16*)alloc(64);

    // cluster sort + conversions (re-done every call: ws is re-poisoned)
    k_init<<<(MPAD + 255) / 256, 256, 0, stream>>>(rowmap, counts, cursors, zerob);
    k_hist<<<B_ROWS / 256, 256, 0, stream>>>(lbl, counts);
    k_offsets<<<1, 256, 0, stream>>>(counts, offs, tilec);
    k_scatter<<<B_ROWS / 256, 256, 0, stream>>>(lbl, offs, cursors, rowmap);
    k_cvt<<<(B_ROWS * 512 / 4 + 255) / 256, 256, 0, stream>>>(x, xh, B_ROWS * 512 / 4);
    k_biasz<<<1, 128, 0, stream>>>(mu_b, lv_b, bz);

    tq_k<<<dim3(32, 16, 1), 256, 0, stream>>>(enc_W0, w0t, 512, 1024, 0, 0);
    tq_k<<<dim3(16, 32, 8), 256, 0, stream>>>(enc_Wu, wut, 1024, 512, 1024l * 512, 512l * 1024);
    tq_k<<<dim3(8, 16, 1), 256, 0, stream>>>(enc_W2, w2t, 512, 256, 0, 0);
    tq_k<<<dim3(2, 8, 1), 256, 0, stream>>>(mu_W, wzt, 256, 64, 0, 0);
    tq_k<<<dim3(2, 8, 1), 256, 0, stream>>>(lv_W, wzt + 64 * 256, 256, 64, 0, 0);
    tq_k<<<dim3(8, 2, 8), 256, 0, stream>>>(dWu0, wd0t, 64, 256, 64l * 256, 256l * 64);
    tq_k<<<dim3(16, 8, 1), 256, 0, stream>>>(dW1, wd1t, 256, 512, 0, 0);
    tq_k<<<dim3(32, 16, 8), 256, 0, stream>>>(dWu2, wd2t, 512, 1024, 512l * 1024, 1024l * 512);
    tq_k<<<dim3(16, 32, 8), 256, 0, stream>>>(finW, wft, 1024, 512, 1024l * 512, 512l * 1024);

    // encoder
    gemm_k<1,0,1,0><<<dim3(MTILES, 8), 256, 0, stream>>>(xh,   w0t,  enc_b0, buf1, nullptr, rowmap, tilec, zerob, 512, 1024);
    gemm_k<0,1,1,0><<<dim3(MTILES, 4), 256, 0, stream>>>(buf1, wut,  enc_bu, buf2, nullptr, rowmap, tilec, zerob, 1024, 512);
    gemm_k<0,0,1,0><<<dim3(MTILES, 2), 256, 0, stream>>>(buf2, w2t,  enc_b2, buf3, nullptr, rowmap, tilec, zerob, 512, 256);
    // latent heads (mu|logvar fused, no relu) + reparameterize
    gemm_k<0,0,0,0><<<dim3(MTILES, 1), 256, 0, stream>>>(buf3, wzt,  bz,     muv,  nullptr, rowmap, tilec, zerob, 256, 128);
    k_reparam<<<MPAD * 64 / 256, 256, 0, stream>>>(muv, eps, rowmap, zb);
    // decoder
    gemm_k<0,1,1,0><<<dim3(MTILES, 2), 256, 0, stream>>>(zb,   wd0t, dbu0,   buf3, nullptr, rowmap, tilec, zerob, 64, 256);
    gemm_k<0,0,1,0><<<dim3(MTILES, 4), 256, 0, stream>>>(buf3, wd1t, db1,    buf2, nullptr, rowmap, tilec, zerob, 256, 512);
    gemm_k<0,1,1,0><<<dim3(MTILES, 8), 256, 0, stream>>>(buf2, wd2t, dbu2,   buf1, nullptr, rowmap, tilec, zerob, 512, 1024);
    // final per-cluster layer, fp32 scatter to d_out
    gemm_k<0,1,0,1><<<dim3(MTILES, 4), 256, 0, stream>>>(buf1, wft,  finb,   nullptr, out,  rowmap, tilec, zerob, 1024, 512);
}

// Round 2
// 395.622 us; speedup vs baseline: 1.1349x; 1.1349x over previous
//
#include <hip/hip_runtime.h>

typedef _Float16 f16;
typedef __attribute__((ext_vector_type(8))) _Float16 f16x8;
typedef __attribute__((ext_vector_type(4))) _Float16 f16x4;
typedef __attribute__((ext_vector_type(4))) float    f32x4;

#define B_ROWS 16384
#define MPAD   17408   // 16384 + 8 clusters * 128-row tile padding
#define MTILES 136
#define NBLK   64      // B_ROWS / 256

typedef __attribute__((address_space(1))) void as1_void;
typedef __attribute__((address_space(3))) void as3_void;

__device__ __forceinline__ void gl_lds16(const void* g, void* l) {
    __builtin_amdgcn_global_load_lds((const as1_void*)g, (as3_void*)l, 16, 0, 0);
}

// ---------------- setup kernels ----------------

__global__ __launch_bounds__(256) void k_init(int* rowmap, f16* zerobuf) {
    int i = blockIdx.x * 256 + threadIdx.x;
    if (i < MPAD) rowmap[i] = -1;
    if (i < 16) zerobuf[i] = (f16)0.f;
}

// per-block histogram: plain stores, no global atomics
__global__ __launch_bounds__(256) void k_hist(const int* __restrict__ lbl, int* __restrict__ blockhist) {
    __shared__ int h[8];
    if (threadIdx.x < 8) h[threadIdx.x] = 0;
    __syncthreads();
    int i = blockIdx.x * 256 + threadIdx.x;
    atomicAdd(&h[lbl[i]], 1);          // LDS atomic, intra-block only
    __syncthreads();
    if (threadIdx.x < 8) blockhist[blockIdx.x * 8 + threadIdx.x] = h[threadIdx.x];
}

// single block: cluster totals -> padded offsets, tile->cluster map, per-block bases
__global__ void k_offsets(const int* __restrict__ blockhist, int* offs, int* tilec, int* blockbase) {
    __shared__ int tot[8];
    __shared__ int so[9];
    int t = threadIdx.x;
    if (t < 8) {
        int s = 0;
        for (int b = 0; b < NBLK; ++b) s += blockhist[b * 8 + t];
        tot[t] = s;
    }
    __syncthreads();
    if (t == 0) {
        int o = 0;
        for (int c = 0; c < 8; ++c) { so[c] = o; o += (tot[c] + 127) & ~127; }
        so[8] = o;
        for (int c = 0; c < 9; ++c) offs[c] = so[c];
    }
    __syncthreads();
    if (t < 8) {
        int run = so[t];
        for (int b = 0; b < NBLK; ++b) {
            blockbase[b * 8 + t] = run;
            run += blockhist[b * 8 + t];
        }
    }
    if (t < MTILES) {
        int row = t * 128, c = 7;
        for (int cc = 0; cc < 8; ++cc)
            if (row >= so[cc] && row < so[cc + 1]) c = cc;
        tilec[t] = c;
    }
}

// scatter: LDS cursors seeded from per-block base — zero contended global atomics
__global__ __launch_bounds__(256) void k_scatter(const int* __restrict__ lbl,
                                                 const int* __restrict__ blockbase,
                                                 int* __restrict__ rowmap) {
    __shared__ int cur[8];
    if (threadIdx.x < 8) cur[threadIdx.x] = blockbase[blockIdx.x * 8 + threadIdx.x];
    __syncthreads();
    int i = blockIdx.x * 256 + threadIdx.x;
    int c = lbl[i];
    int pos = atomicAdd(&cur[c], 1);   // LDS atomic
    rowmap[pos] = i;
}

__global__ __launch_bounds__(256) void k_cvt(const float* __restrict__ s, f16* __restrict__ d, int n4) {
    int i = blockIdx.x * 256 + threadIdx.x;
    if (i < n4) {
        float4 v = ((const float4*)s)[i];
        f16x4 o = {(f16)v.x, (f16)v.y, (f16)v.z, (f16)v.w};
        ((f16x4*)d)[i] = o;
    }
}

// transpose+convert: src [K,N] fp32 -> dst [N,K] f16 (per cluster in grid.z)
__global__ __launch_bounds__(256) void tq_k(const float* __restrict__ src, f16* __restrict__ dst,
                                            int K, int N, long srcCS, long dstCS) {
    __shared__ float t[32][33];
    src += (size_t)blockIdx.z * srcCS;
    dst += (size_t)blockIdx.z * dstCS;
    int n0 = blockIdx.x * 32, k0 = blockIdx.y * 32;
    int tx = threadIdx.x & 31, ty = threadIdx.x >> 5;
    #pragma unroll
    for (int i = 0; i < 32; i += 8)
        t[ty + i][tx] = src[(size_t)(k0 + ty + i) * N + n0 + tx];
    __syncthreads();
    #pragma unroll
    for (int i = 0; i < 32; i += 8)
        dst[(size_t)(n0 + ty + i) * K + k0 + tx] = (f16)t[tx][ty + i];
}

__global__ void k_biasz(const float* __restrict__ mb_, const float* __restrict__ lb_, float* bz) {
    int i = threadIdx.x;
    if (i < 64) bz[i] = mb_[i];
    else if (i < 128) bz[i] = lb_[i - 64];
}

__global__ __launch_bounds__(256) void k_reparam(const f16* __restrict__ muv, const float* __restrict__ eps,
                                                 const int* __restrict__ rowmap, f16* __restrict__ z) {
    int i = blockIdx.x * 256 + threadIdx.x;   // MPAD*64 exactly
    int p = i >> 6, j = i & 63;
    int g = rowmap[p];
    float e  = (g >= 0) ? eps[(size_t)g * 64 + j] : 0.f;
    float mu = (float)muv[(size_t)p * 128 + j];
    float lv = (float)muv[(size_t)p * 128 + 64 + j];
    z[i] = (f16)(mu + expf(0.5f * lv) * e);
}

// ---------------- MFMA GEMM (m97 structure: 128x128 tile, BK=32, global_load_lds) ----------------
// A [*, K] f16 (GATHER: rows via rowmap), Wt [C?, N, K] f16, bias [C?, N] fp32.
// Out f16 [MPAD, N]  (SCATTER: fp32 d_out rows via rowmap)

template<int GATHER, int PERW, int RELU, int SCATTER>
__global__ __launch_bounds__(256) void gemm_k(
    const f16* __restrict__ A, const f16* __restrict__ Wt,
    const float* __restrict__ bias, f16* __restrict__ Out, float* __restrict__ OutF,
    const int* __restrict__ rowmap, const int* __restrict__ tilec,
    const f16* __restrict__ zerobuf, int K, int N)
{
    __shared__ __align__(16) f16 lA[128 * 32];
    __shared__ __align__(16) f16 lB[128 * 32];
    const int tid  = threadIdx.x;
    const int wave = tid >> 6;
    const int lane = tid & 63;
    const int tm = blockIdx.x, tn = blockIdx.y;
    const int r0 = tm * 128, n0 = tn * 128;

    const f16* wb = Wt;
    const float* bb = bias;
    if (PERW) {
        int c = tilec[tm];
        wb += (size_t)c * K * N;
        bb += (size_t)c * N;
    }

    // staging: 256 threads * 16B = one 64-row half-tile per pass; 2 passes each for A and B
    const int srow = tid >> 2;            // 0..63
    const int skk  = (tid & 3) * 8;       // 0,8,16,24 halves
    const f16 *pa0, *pa1;
    int stepA0 = 32, stepA1 = 32;
    if (GATHER) {
        int g0 = rowmap[r0 + srow];
        int g1 = rowmap[r0 + 64 + srow];
        pa0 = (g0 >= 0) ? (A + (size_t)g0 * K + skk) : zerobuf;
        pa1 = (g1 >= 0) ? (A + (size_t)g1 * K + skk) : zerobuf;
        if (g0 < 0) stepA0 = 0;
        if (g1 < 0) stepA1 = 0;
    } else {
        pa0 = A + (size_t)(r0 + srow) * K + skk;
        pa1 = A + (size_t)(r0 + 64 + srow) * K + skk;
    }
    const f16* pb0 = wb + (size_t)(n0 + srow) * K + skk;
    const f16* pb1 = wb + (size_t)(n0 + 64 + srow) * K + skk;

    // wave-uniform LDS staging bases (global_load_lds writes base + lane*16)
    char* lAw = (char*)lA + wave * 1024;
    char* lBw = (char*)lB + wave * 1024;

    const int mb = (wave >> 1) * 64;
    const int nb = (wave & 1) * 64;
    const int quad = lane >> 4;
    const int r16  = lane & 15;

    f32x4 acc[4][4];
    #pragma unroll
    for (int i = 0; i < 4; ++i)
        #pragma unroll
        for (int j = 0; j < 4; ++j)
            acc[i][j] = (f32x4){0.f, 0.f, 0.f, 0.f};

    const int nk = K >> 5;
    for (int kb = 0; kb < nk; ++kb) {
        gl_lds16(pa0, lAw);
        gl_lds16(pa1, lAw + 4096);
        gl_lds16(pb0, lBw);
        gl_lds16(pb1, lBw + 4096);
        __syncthreads();   // compiler emits vmcnt(0) drain before s_barrier
        f16x8 af[4], bf[4];
        #pragma unroll
        for (int i = 0; i < 4; ++i)
            af[i] = *(const f16x8*)(lA + (mb + i * 16 + r16) * 32 + quad * 8);
        #pragma unroll
        for (int j = 0; j < 4; ++j)
            bf[j] = *(const f16x8*)(lB + (nb + j * 16 + r16) * 32 + quad * 8);
        #pragma unroll
        for (int i = 0; i < 4; ++i)
            #pragma unroll
            for (int j = 0; j < 4; ++j)
                acc[i][j] = __builtin_amdgcn_mfma_f32_16x16x32_f16(af[i], bf[j], acc[i][j], 0, 0, 0);
        __syncthreads();
        pa0 += stepA0; pa1 += stepA1; pb0 += 32; pb1 += 32;
    }

    float bv[4];
    #pragma unroll
    for (int j = 0; j < 4; ++j) bv[j] = bb[n0 + nb + j * 16 + r16];

    #pragma unroll
    for (int i = 0; i < 4; ++i) {
        #pragma unroll
        for (int r = 0; r < 4; ++r) {
            int orow = r0 + mb + i * 16 + quad * 4 + r;
            int g = 0;
            if (SCATTER) g = rowmap[orow];
            #pragma unroll
            for (int j = 0; j < 4; ++j) {
                int ocol = n0 + nb + j * 16 + r16;
                float v = acc[i][j][r] + bv[j];
                if (RELU) v = fmaxf(v, 0.f);
                if (SCATTER) {
                    if (g >= 0) OutF[(size_t)g * N + ocol] = v;
                } else {
                    Out[(size_t)orow * N + ocol] = (f16)v;
                }
            }
        }
    }
}

// ---------------- launch ----------------

extern "C" void kernel_launch(void* const* d_in, const int* in_sizes, int n_in,
                              void* d_out, int out_size, void* d_ws, size_t ws_size,
                              hipStream_t stream) {
    const float* x      = (const float*)d_in[0];
    const int*   lbl    = (const int*)  d_in[1];
    const float* eps    = (const float*)d_in[2];
    const float* enc_W0 = (const float*)d_in[3];
    const float* enc_b0 = (const float*)d_in[4];
    const float* enc_Wu = (const float*)d_in[5];
    const float* enc_bu = (const float*)d_in[6];
    const float* enc_W2 = (const float*)d_in[7];
    const float* enc_b2 = (const float*)d_in[8];
    const float* mu_W   = (const float*)d_in[9];
    const float* mu_b   = (const float*)d_in[10];
    const float* lv_W   = (const float*)d_in[11];
    const float* lv_b   = (const float*)d_in[12];
    const float* dWu0   = (const float*)d_in[13];
    const float* dbu0   = (const float*)d_in[14];
    const float* dW1    = (const float*)d_in[15];
    const float* db1    = (const float*)d_in[16];
    const float* dWu2   = (const float*)d_in[17];
    const float* dbu2   = (const float*)d_in[18];
    const float* finW   = (const float*)d_in[19];
    const float* finb   = (const float*)d_in[20];
    float* out = (float*)d_out;
    (void)in_sizes; (void)n_in; (void)out_size; (void)ws_size;

    char* base = (char*)d_ws;
    size_t off = 0;
    auto alloc = [&](size_t bytes) { char* r = base + off; off = (off + bytes + 255) & ~(size_t)255; return r; };
    f16* xh     = (f16*)alloc((size_t)B_ROWS * 512 * 2);
    f16* buf1   = (f16*)alloc((size_t)MPAD * 1024 * 2);  // h1 / h6
    f16* buf2   = (f16*)alloc((size_t)MPAD * 512 * 2);   // h2 / h5
    f16* buf3   = (f16*)alloc((size_t)MPAD * 256 * 2);   // h3 / h4
    f16* muv    = (f16*)alloc((size_t)MPAD * 128 * 2);   // [mu|logvar]
    f16* zb     = (f16*)alloc((size_t)MPAD * 64 * 2);
    f16* w0t    = (f16*)alloc(1024ul * 512 * 2);
    f16* wut    = (f16*)alloc(8ul * 512 * 1024 * 2);
    f16* w2t    = (f16*)alloc(256ul * 512 * 2);
    f16* wzt    = (f16*)alloc(128ul * 256 * 2);
    f16* wd0t   = (f16*)alloc(8ul * 256 * 64 * 2);
    f16* wd1t   = (f16*)alloc(512ul * 256 * 2);
    f16* wd2t   = (f16*)alloc(8ul * 1024 * 512 * 2);
    f16* wft    = (f16*)alloc(8ul * 512 * 1024 * 2);
    float* bz   = (float*)alloc(128 * 4);
    int* rowmap = (int*)alloc(MPAD * 4);
    int* blockhist = (int*)alloc(NBLK * 8 * 4);
    int* blockbase = (int*)alloc(NBLK * 8 * 4);
    int* offs   = (int*)alloc(64);
    int* tilec  = (int*)alloc(MTILES * 4);
    f16* zerob  = (f16*)alloc(64);

    // cluster sort + conversions (re-done every call: ws is re-poisoned)
    k_init<<<(MPAD + 255) / 256, 256, 0, stream>>>(rowmap, zerob);
    k_hist<<<NBLK, 256, 0, stream>>>(lbl, blockhist);
    k_offsets<<<1, 256, 0, stream>>>(blockhist, offs, tilec, blockbase);
    k_scatter<<<NBLK, 256, 0, stream>>>(lbl, blockbase, rowmap);
    k_cvt<<<(B_ROWS * 512 / 4 + 255) / 256, 256, 0, stream>>>(x, xh, B_ROWS * 512 / 4);
    k_biasz<<<1, 128, 0, stream>>>(mu_b, lv_b, bz);

    tq_k<<<dim3(32, 16, 1), 256, 0, stream>>>(enc_W0, w0t, 512, 1024, 0, 0);
    tq_k<<<dim3(16, 32, 8), 256, 0, stream>>>(enc_Wu, wut, 1024, 512, 1024l * 512, 512l * 1024);
    tq_k<<<dim3(8, 16, 1), 256, 0, stream>>>(enc_W2, w2t, 512, 256, 0, 0);
    tq_k<<<dim3(2, 8, 1), 256, 0, stream>>>(mu_W, wzt, 256, 64, 0, 0);
    tq_k<<<dim3(2, 8, 1), 256, 0, stream>>>(lv_W, wzt + 64 * 256, 256, 64, 0, 0);
    tq_k<<<dim3(8, 2, 8), 256, 0, stream>>>(dWu0, wd0t, 64, 256, 64l * 256, 256l * 64);
    tq_k<<<dim3(16, 8, 1), 256, 0, stream>>>(dW1, wd1t, 256, 512, 0, 0);
    tq_k<<<dim3(32, 16, 8), 256, 0, stream>>>(dWu2, wd2t, 512, 1024, 512l * 1024, 1024l * 512);
    tq_k<<<dim3(16, 32, 8), 256, 0, stream>>>(finW, wft, 1024, 512, 1024l * 512, 512l * 1024);

    // encoder
    gemm_k<1,0,1,0><<<dim3(MTILES, 8), 256, 0, stream>>>(xh,   w0t,  enc_b0, buf1, nullptr, rowmap, tilec, zerob, 512, 1024);
    gemm_k<0,1,1,0><<<dim3(MTILES, 4), 256, 0, stream>>>(buf1, wut,  enc_bu, buf2, nullptr, rowmap, tilec, zerob, 1024, 512);
    gemm_k<0,0,1,0><<<dim3(MTILES, 2), 256, 0, stream>>>(buf2, w2t,  enc_b2, buf3, nullptr, rowmap, tilec, zerob, 512, 256);
    // latent heads (mu|logvar fused, no relu) + reparameterize
    gemm_k<0,0,0,0><<<dim3(MTILES, 1), 256, 0, stream>>>(buf3, wzt,  bz,     muv,  nullptr, rowmap, tilec, zerob, 256, 128);
    k_reparam<<<MPAD * 64 / 256, 256, 0, stream>>>(muv, eps, rowmap, zb);
    // decoder
    gemm_k<0,1,1,0><<<dim3(MTILES, 2), 256, 0, stream>>>(zb,   wd0t, dbu0,   buf3, nullptr, rowmap, tilec, zerob, 64, 256);
    gemm_k<0,0,1,0><<<dim3(MTILES, 4), 256, 0, stream>>>(buf3, wd1t, db1,    buf2, nullptr, rowmap, tilec, zerob, 256, 512);
    gemm_k<0,1,1,0><<<dim3(MTILES, 8), 256, 0, stream>>>(buf2, wd2t, dbu2,   buf1, nullptr, rowmap, tilec, zerob, 512, 1024);
    // final per-cluster layer, fp32 scatter to d_out
    gemm_k<0,1,0,1><<<dim3(MTILES, 4), 256, 0, stream>>>(buf1, wft,  finb,   nullptr, out,  rowmap, tilec, zerob, 1024, 512);
}

// Round 3
// 362.277 us; speedup vs baseline: 1.2394x; 1.0920x over previous
//
#include <hip/hip_runtime.h>

typedef _Float16 f16;
typedef __attribute__((ext_vector_type(8))) _Float16 f16x8;
typedef __attribute__((ext_vector_type(4))) _Float16 f16x4;
typedef __attribute__((ext_vector_type(4))) float    f32x4;

#define B_ROWS 16384
#define MPAD   17408   // 16384 + 8 clusters * 128-row tile padding
#define MTILES 136
#define NBLK   64      // B_ROWS / 256

typedef __attribute__((address_space(1))) void as1_void;
typedef __attribute__((address_space(3))) void as3_void;

__device__ __forceinline__ void gl_lds16(const void* g, void* l) {
    __builtin_amdgcn_global_load_lds((const as1_void*)g, (as3_void*)l, 16, 0, 0);
}

// ---------------- prep: rowmap init + per-block histogram + bias concat + zerobuf ----------------

__global__ __launch_bounds__(256) void k_prep(const int* __restrict__ lbl, int* __restrict__ blockhist,
                                              int* __restrict__ rowmap,
                                              const float* __restrict__ mb_, const float* __restrict__ lb_,
                                              float* __restrict__ bz, f16* __restrict__ zerob) {
    int b = blockIdx.x, t = threadIdx.x;
    int i = b * 256 + t;               // grid = 68 blocks -> MPAD exactly
    rowmap[i] = -1;
    if (b < NBLK) {
        __shared__ int h[8];
        if (t < 8) h[t] = 0;
        __syncthreads();
        atomicAdd(&h[lbl[i]], 1);      // LDS atomic
        __syncthreads();
        if (t < 8) blockhist[b * 8 + t] = h[t];
    } else if (b == NBLK) {
        if (t < 64) zerob[t] = (f16)0.f;       // 128 B of zeros
        if (t < 64) bz[t] = mb_[t];
        else if (t < 128) bz[t] = lb_[t - 64];
    }
}

// single block: cluster totals -> padded offsets, tile->cluster map, per-block bases
__global__ void k_offsets(const int* __restrict__ blockhist, int* offs, int* tilec, int* blockbase) {
    __shared__ int tot[8];
    __shared__ int so[9];
    int t = threadIdx.x;
    if (t < 8) {
        int s = 0;
        for (int b = 0; b < NBLK; ++b) s += blockhist[b * 8 + t];
        tot[t] = s;
    }
    __syncthreads();
    if (t == 0) {
        int o = 0;
        for (int c = 0; c < 8; ++c) { so[c] = o; o += (tot[c] + 127) & ~127; }
        so[8] = o;
        for (int c = 0; c < 9; ++c) offs[c] = so[c];
    }
    __syncthreads();
    if (t < 8) {
        int run = so[t];
        for (int b = 0; b < NBLK; ++b) {
            blockbase[b * 8 + t] = run;
            run += blockhist[b * 8 + t];
        }
    }
    if (t < MTILES) {
        int row = t * 128, c = 7;
        for (int cc = 0; cc < 8; ++cc)
            if (row >= so[cc] && row < so[cc + 1]) c = cc;
        tilec[t] = c;
    }
}

// scatter: LDS cursors seeded from per-block base — zero contended global atomics
__global__ __launch_bounds__(256) void k_scatter(const int* __restrict__ lbl,
                                                 const int* __restrict__ blockbase,
                                                 int* __restrict__ rowmap) {
    __shared__ int cur[8];
    if (threadIdx.x < 8) cur[threadIdx.x] = blockbase[blockIdx.x * 8 + threadIdx.x];
    __syncthreads();
    int i = blockIdx.x * 256 + threadIdx.x;
    int c = lbl[i];
    int pos = atomicAdd(&cur[c], 1);   // LDS atomic
    rowmap[pos] = i;
}

// ---------------- merged convert + 9 weight transposes (one dispatch) ----------------
// seg 0: x fp32 -> xh f16 (flat).  segs 1..9: [K,N] fp32 -> [N,K] f16, 32x32 tiles, nz clusters.

struct Seg { const float* s; f16* d; int K, N, b0, nx, ny; long sCS, dCS; };
struct SegTab { Seg g[10]; };

__global__ __launch_bounds__(256) void k_trans(SegTab tab, const float* __restrict__ x, f16* __restrict__ xh) {
    int bid = blockIdx.x;
    if (bid < tab.g[1].b0) {           // cvt segment
        int i = bid * 256 + threadIdx.x;   // n4 = B_ROWS*512/4 = cvt blocks * 256 exactly
        float4 v = ((const float4*)x)[i];
        f16x4 o = {(f16)v.x, (f16)v.y, (f16)v.z, (f16)v.w};
        ((f16x4*)xh)[i] = o;
        return;
    }
    int s = 9;
    while (bid < tab.g[s].b0) --s;     // block-uniform linear search
    Seg sg = tab.g[s];
    int lb = bid - sg.b0;
    int nxy = sg.nx * sg.ny;
    int z = lb / nxy; int r = lb - z * nxy;
    int by = r / sg.nx; int bx = r - by * sg.nx;
    const float* src = sg.s + (size_t)z * sg.sCS;
    f16* dst = sg.d + (size_t)z * sg.dCS;
    int n0 = bx * 32, k0 = by * 32;
    int tx = threadIdx.x & 31, ty = threadIdx.x >> 5;
    __shared__ float t[32][33];
    #pragma unroll
    for (int i = 0; i < 32; i += 8)
        t[ty + i][tx] = src[(size_t)(k0 + ty + i) * sg.N + n0 + tx];
    __syncthreads();
    #pragma unroll
    for (int i = 0; i < 32; i += 8)
        dst[(size_t)(n0 + ty + i) * sg.K + k0 + tx] = (f16)t[tx][ty + i];
}

__global__ __launch_bounds__(256) void k_reparam(const f16* __restrict__ muv, const float* __restrict__ eps,
                                                 const int* __restrict__ rowmap, f16* __restrict__ z) {
    int i = blockIdx.x * 256 + threadIdx.x;   // MPAD*64 exactly
    int p = i >> 6, j = i & 63;
    int g = rowmap[p];
    float e  = (g >= 0) ? eps[(size_t)g * 64 + j] : 0.f;
    float mu = (float)muv[(size_t)p * 128 + j];
    float lv = (float)muv[(size_t)p * 128 + 64 + j];
    z[i] = (f16)(mu + expf(0.5f * lv) * e);
}

// ---------------- MFMA GEMM: 128x128 tile, BK=64, XOR-swizzled LDS, XCD-aware 1-D grid ----------
// A [*, K] f16 (GATHER: rows via rowmap), Wt [C?, N, K] f16, bias [C?, N] fp32.
// Out f16 [MPAD, N]  (SCATTER: fp32 d_out rows via rowmap)
// LDS layout: [row][granule] 16B granules, 8/row; slot g holds global granule g ^ (row&7).
// ds_read_b128 across a quad then hits 8 distinct bank-quads (2-way alias = free, m136).

template<int GATHER, int PERW, int RELU, int SCATTER>
__global__ __launch_bounds__(256) void gemm_k(
    const f16* __restrict__ A, const f16* __restrict__ Wt,
    const float* __restrict__ bias, f16* __restrict__ Out, float* __restrict__ OutF,
    const int* __restrict__ rowmap, const int* __restrict__ tilec,
    const f16* __restrict__ zerobuf, int K, int N)
{
    __shared__ __align__(16) f16 lA[128 * 64];   // 16 KB
    __shared__ __align__(16) f16 lB[128 * 64];   // 16 KB
    const int tid  = threadIdx.x;
    const int wave = tid >> 6;
    const int lane = tid & 63;

    // XCD-aware swizzle: blocks sharing an A row-tile (same tm) land on the same XCD (id mod 8)
    const int id  = blockIdx.x;
    const int xcd = id & 7;
    const int jj  = id >> 3;
    const int tm  = (jj % 17) * 8 + xcd;   // 0..135
    const int tn  = jj / 17;
    const int r0 = tm * 128, n0 = tn * 128;

    const f16* wb = Wt;
    const float* bb = bias;
    if (PERW) {
        int c = tilec[tm];
        wb += (size_t)c * K * N;
        bb += (size_t)c * N;
    }

    // staging: thread t loads granule (sg ^ (srow&7)) of row (pass*32 + srow) each k-chunk
    const int srow = tid >> 3;             // 0..31
    const int sg   = tid & 7;              // 0..7
    const int xk16 = (sg ^ (srow & 7)) * 16;   // r0,n0 are multiples of 128 -> key = srow&7
    const size_t rowB = (size_t)K * 2;     // bytes per row
    const size_t passB = 32 * rowB;        // bytes per 32-row pass group

    const char* pa[4]; size_t stepA[4];
    #pragma unroll
    for (int p = 0; p < 4; ++p) {
        int gr = r0 + p * 32 + srow;
        if (GATHER) {
            int g = rowmap[gr];
            if (g >= 0) { pa[p] = (const char*)(A + (size_t)g * K) + xk16; stepA[p] = 128; }
            else        { pa[p] = (const char*)zerobuf;                    stepA[p] = 0;   }
        } else {
            pa[p] = (const char*)(A + (size_t)gr * K) + xk16; stepA[p] = 128;
        }
    }
    const char* pb = (const char*)(wb + (size_t)(n0 + srow) * K) + xk16;

    const int mb = (wave >> 1) * 64;
    const int nb = (wave & 1) * 64;
    const int quad = lane >> 4;
    const int r16  = lane & 15;
    const int key  = r16 & 7;

    f32x4 acc[4][4];
    #pragma unroll
    for (int i = 0; i < 4; ++i)
        #pragma unroll
        for (int j = 0; j < 4; ++j)
            acc[i][j] = (f32x4){0.f, 0.f, 0.f, 0.f};

    const int nk = K >> 6;
    for (int kb = 0; kb < nk; ++kb) {
        #pragma unroll
        for (int p = 0; p < 4; ++p)
            gl_lds16(pa[p], (char*)lA + p * 4096 + wave * 1024);
        #pragma unroll
        for (int p = 0; p < 4; ++p)
            gl_lds16(pb + p * passB, (char*)lB + p * 4096 + wave * 1024);
        __syncthreads();   // vmcnt(0) drain before s_barrier
        #pragma unroll
        for (int kk = 0; kk < 2; ++kk) {
            const int off = ((kk * 4 + quad) ^ key) * 16;
            f16x8 af[4], bf[4];
            #pragma unroll
            for (int i = 0; i < 4; ++i)
                af[i] = *(const f16x8*)((const char*)lA + (mb + i * 16 + r16) * 128 + off);
            #pragma unroll
            for (int j = 0; j < 4; ++j)
                bf[j] = *(const f16x8*)((const char*)lB + (nb + j * 16 + r16) * 128 + off);
            #pragma unroll
            for (int i = 0; i < 4; ++i)
                #pragma unroll
                for (int j = 0; j < 4; ++j)
                    acc[i][j] = __builtin_amdgcn_mfma_f32_16x16x32_f16(af[i], bf[j], acc[i][j], 0, 0, 0);
        }
        __syncthreads();
        #pragma unroll
        for (int p = 0; p < 4; ++p) pa[p] += stepA[p];
        pb += 128;
    }

    float bv[4];
    #pragma unroll
    for (int j = 0; j < 4; ++j) bv[j] = bb[n0 + nb + j * 16 + r16];

    #pragma unroll
    for (int i = 0; i < 4; ++i) {
        #pragma unroll
        for (int r = 0; r < 4; ++r) {
            int orow = r0 + mb + i * 16 + quad * 4 + r;
            int g = 0;
            if (SCATTER) g = rowmap[orow];
            #pragma unroll
            for (int j = 0; j < 4; ++j) {
                int ocol = n0 + nb + j * 16 + r16;
                float v = acc[i][j][r] + bv[j];
                if (RELU) v = fmaxf(v, 0.f);
                if (SCATTER) {
                    if (g >= 0) OutF[(size_t)g * N + ocol] = v;
                } else {
                    Out[(size_t)orow * N + ocol] = (f16)v;
                }
            }
        }
    }
}

// ---------------- launch ----------------

extern "C" void kernel_launch(void* const* d_in, const int* in_sizes, int n_in,
                              void* d_out, int out_size, void* d_ws, size_t ws_size,
                              hipStream_t stream) {
    const float* x      = (const float*)d_in[0];
    const int*   lbl    = (const int*)  d_in[1];
    const float* eps    = (const float*)d_in[2];
    const float* enc_W0 = (const float*)d_in[3];
    const float* enc_b0 = (const float*)d_in[4];
    const float* enc_Wu = (const float*)d_in[5];
    const float* enc_bu = (const float*)d_in[6];
    const float* enc_W2 = (const float*)d_in[7];
    const float* enc_b2 = (const float*)d_in[8];
    const float* mu_W   = (const float*)d_in[9];
    const float* mu_b   = (const float*)d_in[10];
    const float* lv_W   = (const float*)d_in[11];
    const float* lv_b   = (const float*)d_in[12];
    const float* dWu0   = (const float*)d_in[13];
    const float* dbu0   = (const float*)d_in[14];
    const float* dW1    = (const float*)d_in[15];
    const float* db1    = (const float*)d_in[16];
    const float* dWu2   = (const float*)d_in[17];
    const float* dbu2   = (const float*)d_in[18];
    const float* finW   = (const float*)d_in[19];
    const float* finb   = (const float*)d_in[20];
    float* out = (float*)d_out;
    (void)in_sizes; (void)n_in; (void)out_size; (void)ws_size;

    char* base = (char*)d_ws;
    size_t off = 0;
    auto alloc = [&](size_t bytes) { char* r = base + off; off = (off + bytes + 255) & ~(size_t)255; return r; };
    f16* xh     = (f16*)alloc((size_t)B_ROWS * 512 * 2);
    f16* buf1   = (f16*)alloc((size_t)MPAD * 1024 * 2);  // h1 / h6
    f16* buf2   = (f16*)alloc((size_t)MPAD * 512 * 2);   // h2 / h5
    f16* buf3   = (f16*)alloc((size_t)MPAD * 256 * 2);   // h3 / h4
    f16* muv    = (f16*)alloc((size_t)MPAD * 128 * 2);   // [mu|logvar]
    f16* zb     = (f16*)alloc((size_t)MPAD * 64 * 2);
    f16* w0t    = (f16*)alloc(1024ul * 512 * 2);
    f16* wut    = (f16*)alloc(8ul * 512 * 1024 * 2);
    f16* w2t    = (f16*)alloc(256ul * 512 * 2);
    f16* wzt    = (f16*)alloc(128ul * 256 * 2);
    f16* wd0t   = (f16*)alloc(8ul * 256 * 64 * 2);
    f16* wd1t   = (f16*)alloc(512ul * 256 * 2);
    f16* wd2t   = (f16*)alloc(8ul * 1024 * 512 * 2);
    f16* wft    = (f16*)alloc(8ul * 512 * 1024 * 2);
    float* bz   = (float*)alloc(128 * 4);
    int* rowmap = (int*)alloc(MPAD * 4);
    int* blockhist = (int*)alloc(NBLK * 8 * 4);
    int* blockbase = (int*)alloc(NBLK * 8 * 4);
    int* offs   = (int*)alloc(64);
    int* tilec  = (int*)alloc(MTILES * 4);
    f16* zerob  = (f16*)alloc(256);

    // cluster sort + bias concat
    k_prep<<<MPAD / 256, 256, 0, stream>>>(lbl, blockhist, rowmap, mu_b, lv_b, bz, zerob);
    k_offsets<<<1, 256, 0, stream>>>(blockhist, offs, tilec, blockbase);
    k_scatter<<<NBLK, 256, 0, stream>>>(lbl, blockbase, rowmap);

    // merged convert + transposes: seg0 cvt (8192 blocks), segs 1..9 transposes
    SegTab tab;
    int b0 = B_ROWS * 512 / 4 / 256;   // 8192
    auto seg = [&](int i, const float* s, f16* d, int K, int N, int nz, long sCS, long dCS) {
        int nx = N / 32, ny = K / 32;
        tab.g[i] = Seg{s, d, K, N, b0, nx, ny, sCS, dCS};
        b0 += nx * ny * nz;
    };
    tab.g[0] = Seg{nullptr, nullptr, 0, 0, 0, 0, 0, 0, 0};
    seg(1, enc_W0, w0t, 512, 1024, 1, 0, 0);
    seg(2, enc_Wu, wut, 1024, 512, 8, 1024l * 512, 512l * 1024);
    seg(3, enc_W2, w2t, 512, 256, 1, 0, 0);
    seg(4, mu_W, wzt, 256, 64, 1, 0, 0);
    seg(5, lv_W, wzt + 64 * 256, 256, 64, 1, 0, 0);
    seg(6, dWu0, wd0t, 64, 256, 8, 64l * 256, 256l * 64);
    seg(7, dW1, wd1t, 256, 512, 1, 0, 0);
    seg(8, dWu2, wd2t, 512, 1024, 8, 512l * 1024, 1024l * 512);
    seg(9, finW, wft, 1024, 512, 8, 1024l * 512, 512l * 1024);
    k_trans<<<b0, 256, 0, stream>>>(tab, x, xh);

    // encoder
    gemm_k<1,0,1,0><<<MTILES * 8, 256, 0, stream>>>(xh,   w0t,  enc_b0, buf1, nullptr, rowmap, tilec, zerob, 512, 1024);
    gemm_k<0,1,1,0><<<MTILES * 4, 256, 0, stream>>>(buf1, wut,  enc_bu, buf2, nullptr, rowmap, tilec, zerob, 1024, 512);
    gemm_k<0,0,1,0><<<MTILES * 2, 256, 0, stream>>>(buf2, w2t,  enc_b2, buf3, nullptr, rowmap, tilec, zerob, 512, 256);
    // latent heads (mu|logvar fused, no relu) + reparameterize
    gemm_k<0,0,0,0><<<MTILES * 1, 256, 0, stream>>>(buf3, wzt,  bz,     muv,  nullptr, rowmap, tilec, zerob, 256, 128);
    k_reparam<<<MPAD * 64 / 256, 256, 0, stream>>>(muv, eps, rowmap, zb);
    // decoder
    gemm_k<0,1,1,0><<<MTILES * 2, 256, 0, stream>>>(zb,   wd0t, dbu0,   buf3, nullptr, rowmap, tilec, zerob, 64, 256);
    gemm_k<0,0,1,0><<<MTILES * 4, 256, 0, stream>>>(buf3, wd1t, db1,    buf2, nullptr, rowmap, tilec, zerob, 256, 512);
    gemm_k<0,1,1,0><<<MTILES * 8, 256, 0, stream>>>(buf2, wd2t, dbu2,   buf1, nullptr, rowmap, tilec, zerob, 512, 1024);
    // final per-cluster layer, fp32 scatter to d_out
    gemm_k<0,1,0,1><<<MTILES * 4, 256, 0, stream>>>(buf1, wft,  finb,   nullptr, out,  rowmap, tilec, zerob, 1024, 512);
}